// Round 1
// baseline (6844.385 us; speedup 1.0000x reference)
//
#include <hip/hip_runtime.h>
#include <math.h>

#define NLM 25
#define FE 144
#define NPATH 65
#define NSLOT 375
#define MAXE 81

// ======================= CG init (runs every launch; ~µs) =======================

__device__ inline double lfac(const double* fact, int n){ return log(fact[n]); }

__device__ double cg_complex_dev(int l1,int m1,int l2,int m2,int l3,int m3,const double* fact){
  if(m1+m2!=m3) return 0.0;
  if(l3 < abs(l1-l2) || l3 > l1+l2) return 0.0;
  double pre = 0.5*( lfac(fact,l1+l2-l3)+lfac(fact,l1-l2+l3)+lfac(fact,-l1+l2+l3)-lfac(fact,l1+l2+l3+1)
    + lfac(fact,l1+m1)+lfac(fact,l1-m1)+lfac(fact,l2+m2)+lfac(fact,l2-m2)+lfac(fact,l3+m3)+lfac(fact,l3-m3));
  int kmin = max(0, max(l2-l3-m1, l1-l3+m2));
  int kmax = min(l1+l2-l3, min(l1-m1, l2+m2));
  double s=0.0;
  for(int k=kmin;k<=kmax;k++){
    double ln = lfac(fact,k)+lfac(fact,l1+l2-l3-k)+lfac(fact,l1-m1-k)+lfac(fact,l2+m2-k)
               +lfac(fact,l3-l2+m1+k)+lfac(fact,l3-l1-m2+k);
    s += ((k&1)? -1.0:1.0)*exp(pre-ln);
  }
  return sqrt((double)(2*l3+1))*s;
}

__device__ inline int l_of_idx(int idx){ int l=0; while((l+1)*(l+1)<=idx) l++; return l; }

// nonzeros of row `idx` of the complex->real U matrix (block-diagonal per l, <=2 nnz/row)
__device__ inline int urow_dev(int idx,int l,int* cols,double* ure,double* uim){
  const double is2 = 0.70710678118654752440;
  int off=l*l+l, m=idx-off;
  if(m==0){cols[0]=off;ure[0]=1.0;uim[0]=0.0;return 1;}
  if(m>0){
    double sgn=(m&1)?-1.0:1.0;
    cols[0]=off+m; ure[0]=sgn*is2; uim[0]=0.0;
    cols[1]=off-m; ure[1]=is2;     uim[1]=0.0;
    return 2;
  }
  int mm=-m; double sgn=(mm&1)?-1.0:1.0;
  cols[0]=off-mm; ure[0]=0.0; uim[0]=is2;
  cols[1]=off+mm; ure[1]=0.0; uim[1]=-sgn*is2;
  return 2;
}

// one thread per (i,j,k) of the dense 25^3 real-CG tensor; thread 0 also builds the
// path table; first N threads zero the CSR count array (saves a memset launch).
__global__ __launch_bounds__(64) void k_cg(float* CGd, int* ptab, int* cnt, int N){
  int t = blockIdx.x*blockDim.x + threadIdx.x;
  if(t<N) cnt[t]=0;
  if(t==0){
    int pi=0, sbase=0;
    for(int l1=0;l1<=4;l1++)for(int l2=0;l2<=4;l2++){
      int lo=abs(l1-l2), hi=min(4,l1+l2);
      for(int l3=lo;l3<=hi;l3++){
        ptab[pi*6+0]=l1*l1; ptab[pi*6+1]=l2*l2; ptab[pi*6+2]=l3*l3;
        ptab[pi*6+3]=(l1+l2+l3)&1; ptab[pi*6+4]=sbase; ptab[pi*6+5]=2*l3+1;
        sbase+=2*l3+1; pi++;
      }
    }
  }
  if(t>=15625) return;
  int i=t/625, j=(t/25)%25, k=t%25;
  double fact[14]; fact[0]=1.0;
  for(int m=1;m<14;m++) fact[m]=fact[m-1]*(double)m;
  int li=l_of_idx(i), lj=l_of_idx(j), lk=l_of_idx(k);
  int ca[2],cb[2],cc[2]; double ra[2],ia_[2],rb[2],ib_[2],rc[2],ic_[2];
  int na=urow_dev(i,li,ca,ra,ia_);
  int nb=urow_dev(j,lj,cb,rb,ib_);
  int nc=urow_dev(k,lk,cc,rc,ic_);
  double Tre=0.0,Tim=0.0;
  for(int a=0;a<na;a++)for(int b=0;b<nb;b++)for(int c=0;c<nc;c++){
    int ma=ca[a]-li*li-li, mb=cb[b]-lj*lj-lj, mc=cc[c]-lk*lk-lk;
    double cg=cg_complex_dev(li,ma,lj,mb,lk,mc,fact);
    if(cg==0.0) continue;
    double xre = ra[a]*rb[b]-ia_[a]*ib_[b];
    double xim = ra[a]*ib_[b]+ia_[a]*rb[b];
    double wre = xre*rc[c]+xim*ic_[c];   // * conj(Uc)
    double wim = xim*rc[c]-xre*ic_[c];
    Tre += wre*cg; Tim += wim*cg;
  }
  double C = Tre+Tim;
  if(fabs(C)<1e-12) C=0.0;
  CGd[t]=(float)C;
}

// compact nonzero (ia,ib) per (path, c) slot
__global__ __launch_bounds__(16) void k_entries(const float* __restrict__ CGd, const int* __restrict__ ptab,
                                                int* eidx, float* eval_, int* ecnt){
  int pi=blockIdx.x, c=threadIdx.x;
  int l1sq=ptab[pi*6], l2sq=ptab[pi*6+1], l3sq=ptab[pi*6+2];
  int sbase=ptab[pi*6+4], n3=ptab[pi*6+5];
  if(c>=n3) return;
  int l1=l_of_idx(l1sq), l2=l_of_idx(l2sq);
  int slot=sbase+c, cntv=0;
  for(int ia=0; ia<2*l1+1; ia++)
    for(int ib=0; ib<2*l2+1; ib++){
      float v = CGd[(l1sq+ia)*625 + (l2sq+ib)*25 + (l3sq+c)];
      if(v!=0.0f){ eidx[slot*MAXE+cntv]=ia|(ib<<8); eval_[slot*MAXE+cntv]=v; cntv++; }
    }
  ecnt[slot]=cntv;
}

// ======================= edge stage =======================

__global__ __launch_bounds__(256) void k_edge(const int* __restrict__ Z, const int* __restrict__ nbr,
    const float* __restrict__ disp, const float* __restrict__ Wsp,
    float* __restrict__ g, float* __restrict__ Ye, int* cnt, int E){
  int e=blockIdx.x*256+threadIdx.x; if(e>=E) return;
  int i0=nbr[2*e], j0=nbr[2*e+1];
  atomicAdd(&cnt[i0],1);
  int z=Z[j0];
  float dx=disp[3*e], dy=disp[3*e+1], dz=disp[3*e+2];
  float r=sqrtf(dx*dx+dy*dy+dz*dz+1e-12f);
  float inv=1.0f/r;
  float x=dx*inv, y=dy*inv, zz=dz*inv;
  float rc=fminf(r*0.2f,1.0f);
  float fc=0.5f*(cosf(3.14159265358979323846f*rc)+1.0f);
  float rbf[16];
  #pragma unroll
  for(int k=0;k<16;k++){
    float d=r-(float)k*(5.0f/15.0f);
    rbf[k]=expf(-10.24f*d*d)*fc;
  }
  const float* Wz=Wsp + z*256;
  #pragma unroll
  for(int rr=0;rr<16;rr++){
    float s=0.f;
    #pragma unroll
    for(int k=0;k<16;k++) s += rbf[k]*Wz[k*16+rr];
    g[e*16+rr]=s;
  }
  float x2=x*x,y2=y*y,z2=zz*zz;
  float* Y=Ye+(size_t)e*25;
  Y[0]=0.28209479177387814f;
  Y[1]=0.4886025119029199f*y;
  Y[2]=0.4886025119029199f*zz;
  Y[3]=0.4886025119029199f*x;
  Y[4]=1.0925484305920792f*x*y;
  Y[5]=1.0925484305920792f*y*zz;
  Y[6]=0.31539156525252005f*(3.f*z2-1.f);
  Y[7]=1.0925484305920792f*x*zz;
  Y[8]=0.5462742152960396f*(x2-y2);
  Y[9]=0.5900435899266435f*y*(3.f*x2-y2);
  Y[10]=2.890611442640554f*x*y*zz;
  Y[11]=0.4570457994644658f*y*(5.f*z2-1.f);
  Y[12]=0.3731763325901154f*zz*(5.f*z2-3.f);
  Y[13]=0.4570457994644658f*x*(5.f*z2-1.f);
  Y[14]=1.445305721320277f*zz*(x2-y2);
  Y[15]=0.5900435899266435f*x*(x2-3.f*y2);
  Y[16]=2.5033429417967046f*x*y*(x2-y2);
  Y[17]=1.7701307697799304f*y*zz*(3.f*x2-y2);
  Y[18]=0.9461746957575601f*x*y*(7.f*z2-1.f);
  Y[19]=0.6690465435572892f*y*zz*(7.f*z2-3.f);
  Y[20]=0.10578554691520431f*(35.f*z2*z2-30.f*z2+3.f);
  Y[21]=0.6690465435572892f*x*zz*(7.f*z2-3.f);
  Y[22]=0.47308734787878004f*(x2-y2)*(7.f*z2-1.f);
  Y[23]=1.7701307697799304f*x*zz*(x2-3.f*y2);
  Y[24]=0.6258357354491761f*(x2*x2-6.f*x2*y2+y2*y2);
}

// ======================= CSR build =======================

__global__ __launch_bounds__(1024) void k_scan(const int* __restrict__ cnt, int* offs, int* cursor, int N){
  __shared__ int part[1024];
  int t=threadIdx.x;
  int per=(N+1023)>>10;
  int start=t*per;
  int s=0;
  for(int i2=0;i2<per;i2++){int idx=start+i2; if(idx<N) s+=cnt[idx];}
  part[t]=s; __syncthreads();
  for(int off=1;off<1024;off<<=1){
    int v=(t>=off)?part[t-off]:0;
    __syncthreads();
    part[t]+=v;
    __syncthreads();
  }
  int run=(t>0)?part[t-1]:0;
  for(int i2=0;i2<per;i2++){int idx=start+i2; if(idx<N){offs[idx]=run; cursor[idx]=run; run+=cnt[idx];}}
  if(t==1023) offs[N]=part[1023];
}

__global__ __launch_bounds__(256) void k_fill(const int* __restrict__ nbr, int* cursor, int* elist, int E){
  int e=blockIdx.x*256+threadIdx.x; if(e>=E)return;
  int pos=atomicAdd(&cursor[nbr[2*e]],1);
  elist[pos]=e;
}

// ======================= aggregation: y0 -> d_out ch 0..15 =======================

__global__ __launch_bounds__(64) void k_agg(const float* __restrict__ g, const float* __restrict__ Ye,
    const int* __restrict__ offs, const int* __restrict__ elist, const float* __restrict__ norm,
    float* __restrict__ y){
  int n=blockIdx.x, t=threadIdx.x;
  __shared__ float gs[16];
  __shared__ float ys[25];
  float acc[7];
  #pragma unroll
  for(int i2=0;i2<7;i2++) acc[i2]=0.f;
  int e0=offs[n], e1=offs[n+1];
  for(int ei=e0; ei<e1; ei++){
    int e=elist[ei];
    if(t<16) gs[t]=g[(size_t)e*16+t];
    else if(t<41) ys[t-16]=Ye[(size_t)e*25+t-16];
    __syncthreads();
    #pragma unroll
    for(int i2=0;i2<7;i2++){
      int o=t+64*i2;
      if(o<400) acc[i2] += ys[o>>4]*gs[o&15];
    }
    __syncthreads();
  }
  float nv=1.0f/norm[0];
  float* yo=y+(size_t)n*7200;
  #pragma unroll
  for(int i2=0;i2<7;i2++){
    int o=t+64*i2;
    if(o<400){ int lm=o>>4,k=o&15; yo[lm*144+k]=acc[i2]*nv; yo[3600+lm*144+k]=0.f; }
  }
}

// ======================= TP layer 0 (input parity-0 only) =======================

__global__ __launch_bounds__(64) void k_tp0(float* __restrict__ y, const float* __restrict__ W1,
    const float* __restrict__ W2, const float* __restrict__ wp, const int* __restrict__ ptab,
    const int* __restrict__ eidx, const float* __restrict__ eval_, const int* __restrict__ ecnt){
  int n=blockIdx.x, f=threadIdx.x;
  __shared__ float y0s[400];
  __shared__ float aS[1600];
  __shared__ float bS[1600];
  __shared__ float outS[3200];
  const float* yin = y + (size_t)n*7200;
  for(int t=f;t<400;t+=64) y0s[t] = yin[(t>>4)*144 + (t&15)];
  for(int t=f;t<3200;t+=64) outS[t]=0.f;
  __syncthreads();
  // degree-dense (a,b), parity 0 only
  #pragma unroll
  for(int l=0;l<5;l++){
    const int n1=2*l+1, base=l*l;
    float accA[9],accB[9];
    #pragma unroll
    for(int j2=0;j2<9;j2++){accA[j2]=0.f;accB[j2]=0.f;}
    const float* w1=W1+l*1024+f;
    const float* w2=W2+l*1024+f;
    for(int k=0;k<16;k++){
      float u1=w1[k*64], u2=w2[k*64];
      #pragma unroll
      for(int j2=0;j2<n1;j2++){
        float yv=y0s[(base+j2)*16+k];
        accA[j2]+=yv*u1; accB[j2]+=yv*u2;
      }
    }
    #pragma unroll
    for(int j2=0;j2<n1;j2++){ aS[(base+j2)*64+f]=accA[j2]; bS[(base+j2)*64+f]=accB[j2]; }
  }
  __syncthreads();
  // sparse CG contraction; only (p,q)=(0,0) contributes
  for(int pi=0;pi<NPATH;pi++){
    int l1sq=ptab[pi*6], l2sq=ptab[pi*6+1], l3sq=ptab[pi*6+2];
    int s=ptab[pi*6+3], sbase=ptab[pi*6+4], n3=ptab[pi*6+5];
    float w00=wp[pi*256+f];
    for(int c=0;c<n3;c++){
      int slot=sbase+c;
      int cntv=ecnt[slot];
      const int* ei=eidx+slot*MAXE;
      const float* ev=eval_+slot*MAXE;
      float r=0.f;
      for(int j2=0;j2<cntv;j2++){
        int e=ei[j2]; float v=ev[j2];
        r += v*aS[(l1sq+(e&255))*64+f]*bS[(l2sq+(e>>8))*64+f];
      }
      outS[(s*25+l3sq+c)*64+f] += w00*r;
    }
  }
  __syncthreads();
  float* yo = y + (size_t)n*7200 + 16;
  for(int t2=0;t2<50;t2++) yo[t2*144+f]=outS[t2*64+f];
}

// ======================= TP layer 1 (both parities) =======================

__global__ __launch_bounds__(64) void k_tp1(float* __restrict__ y, const float* __restrict__ W1,
    const float* __restrict__ W2, const float* __restrict__ wp, const int* __restrict__ ptab,
    const int* __restrict__ eidx, const float* __restrict__ eval_, const int* __restrict__ ecnt){
  int n=blockIdx.x, f=threadIdx.x;
  __shared__ float y1s[3200];
  __shared__ float2 aS[1600];   // [lm*64+f] = (parity0, parity1)
  __shared__ float2 bS[1600];
  __shared__ float outS[3200];
  const float* yin = y + (size_t)n*7200 + 16;
  for(int t=f;t<3200;t+=64){ y1s[t]=yin[(t>>6)*144+(t&63)]; outS[t]=0.f; }
  __syncthreads();
  #pragma unroll
  for(int p=0;p<2;p++){
    #pragma unroll
    for(int l=0;l<5;l++){
      const int n1=2*l+1, base=l*l;
      float accA[9],accB[9];
      #pragma unroll
      for(int j2=0;j2<9;j2++){accA[j2]=0.f;accB[j2]=0.f;}
      const float* w1=W1+(p*5+l)*4096+f;
      const float* w2=W2+(p*5+l)*4096+f;
      for(int k=0;k<64;k++){
        float u1=w1[k*64], u2=w2[k*64];
        #pragma unroll
        for(int j2=0;j2<n1;j2++){
          float yv=y1s[(p*25+base+j2)*64+k];
          accA[j2]+=yv*u1; accB[j2]+=yv*u2;
        }
      }
      #pragma unroll
      for(int j2=0;j2<n1;j2++){
        if(p==0){ aS[(base+j2)*64+f].x=accA[j2]; bS[(base+j2)*64+f].x=accB[j2]; }
        else    { aS[(base+j2)*64+f].y=accA[j2]; bS[(base+j2)*64+f].y=accB[j2]; }
      }
    }
  }
  __syncthreads();
  for(int pi=0;pi<NPATH;pi++){
    int l1sq=ptab[pi*6], l2sq=ptab[pi*6+1], l3sq=ptab[pi*6+2];
    int s=ptab[pi*6+3], sbase=ptab[pi*6+4], n3=ptab[pi*6+5];
    float w00=wp[pi*256+f], w01=wp[pi*256+64+f], w10=wp[pi*256+128+f], w11=wp[pi*256+192+f];
    for(int c=0;c<n3;c++){
      int slot=sbase+c;
      int cntv=ecnt[slot];
      const int* ei=eidx+slot*MAXE;
      const float* ev=eval_+slot*MAXE;
      float r00=0.f,r01=0.f,r10=0.f,r11=0.f;
      for(int j2=0;j2<cntv;j2++){
        int e=ei[j2]; float v=ev[j2];
        float2 av=aS[(l1sq+(e&255))*64+f];
        float2 bv=bS[(l2sq+(e>>8))*64+f];
        r00+=v*av.x*bv.x; r01+=v*av.x*bv.y; r10+=v*av.y*bv.x; r11+=v*av.y*bv.y;
      }
      outS[(s*25+l3sq+c)*64+f]      += w00*r00+w11*r11;   // even
      outS[((1-s)*25+l3sq+c)*64+f]  += w01*r01+w10*r10;   // odd
    }
  }
  __syncthreads();
  float* yo=y+(size_t)n*7200+80;
  for(int t2=0;t2<50;t2++) yo[t2*144+f]=outS[t2*64+f];
}

// ======================= final: te scale + (0,0)+=te + y + y*tanh(softplus(y)) =======================

__device__ const int DEGLM[25]={0,1,1,1,2,2,2,2,2,3,3,3,3,3,3,3,4,4,4,4,4,4,4,4,4};

__global__ __launch_bounds__(128) void k_final(float* __restrict__ y, const int* __restrict__ Z,
    const float* __restrict__ emb, const float* __restrict__ Wet, const float* __restrict__ bet,
    const float* __restrict__ wf){
  int n=blockIdx.x, t=threadIdx.x;
  __shared__ float embs[64];
  __shared__ float teS[144];
  int z=Z[n];
  if(t<64) embs[t]=emb[z*64+t];
  __syncthreads();
  for(int c=t;c<144;c+=128){
    float s=bet[c];
    for(int d=0;d<64;d++) s+=embs[d]*Wet[d*144+c];
    teS[c]=s;
  }
  __syncthreads();
  float* yo=y+(size_t)n*7200;
  for(int row=0;row<50;row++){
    int p=row/25, lm=row-25*p;
    const float* wrow=wf+(p*5+DEGLM[lm])*144;
    for(int c=t;c<144;c+=128){
      float v=yo[row*144+c];
      float te=teS[c];
      v=te*v*wrow[c];
      if(row==0) v+=te;
      float sp=log1pf(expf(v));
      v=v+v*tanhf(sp);
      yo[row*144+c]=v;
    }
  }
}

// ======================= launch =======================

extern "C" void kernel_launch(void* const* d_in, const int* in_sizes, int n_in,
                              void* d_out, int out_size, void* d_ws, size_t ws_size,
                              hipStream_t stream) {
  const int*   Z    =(const int*)  d_in[0];
  const int*   nbr  =(const int*)  d_in[1];
  const float* disp =(const float*)d_in[2];
  const float* Wsp  =(const float*)d_in[3];
  const float* emb  =(const float*)d_in[4];
  const float* Wet  =(const float*)d_in[5];
  const float* bet  =(const float*)d_in[6];
  const float* norm =(const float*)d_in[7];
  const float* t0W1 =(const float*)d_in[8];
  const float* t0W2 =(const float*)d_in[9];
  const float* t0wp =(const float*)d_in[10];
  const float* t1W1 =(const float*)d_in[11];
  const float* t1W2 =(const float*)d_in[12];
  const float* t1wp =(const float*)d_in[13];
  const float* wf   =(const float*)d_in[14];
  int N=in_sizes[0];
  int E=in_sizes[1]/2;
  float* y=(float*)d_out;

  char* w=(char*)d_ws;
  size_t off=0;
  auto take=[&](size_t bytes)->void*{ size_t cur=(off+255)&~(size_t)255; off=cur+bytes; return (void*)(w+cur); };
  float* CGd   =(float*)take(15625*4);
  int*   ptab  =(int*)  take(NPATH*6*4);
  int*   eidx  =(int*)  take((size_t)NSLOT*MAXE*4);
  float* eval_ =(float*)take((size_t)NSLOT*MAXE*4);
  int*   ecnt  =(int*)  take(NSLOT*4);
  int*   cnt   =(int*)  take((size_t)N*4);
  int*   offs  =(int*)  take((size_t)(N+1)*4);
  int*   cursor=(int*)  take((size_t)N*4);
  int*   elist =(int*)  take((size_t)E*4);
  float* g     =(float*)take((size_t)E*16*4);
  float* Ye    =(float*)take((size_t)E*25*4);
  (void)ws_size; (void)out_size; (void)n_in;

  k_cg     <<<dim3((15625+63)/64), dim3(64),  0, stream>>>(CGd, ptab, cnt, N);
  k_entries<<<dim3(NPATH),         dim3(16),  0, stream>>>(CGd, ptab, eidx, eval_, ecnt);
  k_edge   <<<dim3((E+255)/256),   dim3(256), 0, stream>>>(Z, nbr, disp, Wsp, g, Ye, cnt, E);
  k_scan   <<<dim3(1),             dim3(1024),0, stream>>>(cnt, offs, cursor, N);
  k_fill   <<<dim3((E+255)/256),   dim3(256), 0, stream>>>(nbr, cursor, elist, E);
  k_agg    <<<dim3(N),             dim3(64),  0, stream>>>(g, Ye, offs, elist, norm, y);
  k_tp0    <<<dim3(N),             dim3(64),  0, stream>>>(y, t0W1, t0W2, t0wp, ptab, eidx, eval_, ecnt);
  k_tp1    <<<dim3(N),             dim3(64),  0, stream>>>(y, t1W1, t1W2, t1wp, ptab, eidx, eval_, ecnt);
  k_final  <<<dim3(N),             dim3(128), 0, stream>>>(y, Z, emb, Wet, bet, wf);
}

// Round 2
// 5441.343 us; speedup vs baseline: 1.2578x; 1.2578x over previous
//
#include <hip/hip_runtime.h>
#include <math.h>

#define NLM 25
#define FE 144
#define NPATH 65
#define NSLOT 375
#define MAXE 81

// ======================= CG init (runs every launch; ~µs) =======================

// direct factorial arithmetic (no log/exp): exp(0.5*logP - log den) == sqrt(P)/den
__device__ double cg_complex_dev(int l1,int m1,int l2,int m2,int l3,int m3,const double* fact){
  if(m1+m2!=m3) return 0.0;
  if(l3 < abs(l1-l2) || l3 > l1+l2) return 0.0;
  double P = fact[l1+l2-l3]*fact[l1-l2+l3]*fact[-l1+l2+l3]/fact[l1+l2+l3+1]
           * fact[l1+m1]*fact[l1-m1]*fact[l2+m2]*fact[l2-m2]*fact[l3+m3]*fact[l3-m3];
  double spre = sqrt(P);
  int kmin = max(0, max(l2-l3-m1, l1-l3+m2));
  int kmax = min(l1+l2-l3, min(l1-m1, l2+m2));
  double s=0.0;
  for(int k=kmin;k<=kmax;k++){
    double den = fact[k]*fact[l1+l2-l3-k]*fact[l1-m1-k]*fact[l2+m2-k]
               * fact[l3-l2+m1+k]*fact[l3-l1-m2+k];
    s += ((k&1)? -1.0:1.0)/den;
  }
  return sqrt((double)(2*l3+1))*spre*s;
}

__device__ inline int l_of_idx(int idx){ int l=0; while((l+1)*(l+1)<=idx) l++; return l; }

__device__ inline int urow_dev(int idx,int l,int* cols,double* ure,double* uim){
  const double is2 = 0.70710678118654752440;
  int off=l*l+l, m=idx-off;
  if(m==0){cols[0]=off;ure[0]=1.0;uim[0]=0.0;return 1;}
  if(m>0){
    double sgn=(m&1)?-1.0:1.0;
    cols[0]=off+m; ure[0]=sgn*is2; uim[0]=0.0;
    cols[1]=off-m; ure[1]=is2;     uim[1]=0.0;
    return 2;
  }
  int mm=-m; double sgn=(mm&1)?-1.0:1.0;
  cols[0]=off-mm; ure[0]=0.0; uim[0]=is2;
  cols[1]=off+mm; ure[1]=0.0; uim[1]=-sgn*is2;
  return 2;
}

__global__ __launch_bounds__(64) void k_cg(float* CGd, int* ptab, int* cnt, int N){
  int t = blockIdx.x*blockDim.x + threadIdx.x;
  if(t<N) cnt[t]=0;
  if(t==0){
    int pi=0, sbase=0;
    for(int l1=0;l1<=4;l1++)for(int l2=0;l2<=4;l2++){
      int lo=abs(l1-l2), hi=min(4,l1+l2);
      for(int l3=lo;l3<=hi;l3++){
        ptab[pi*6+0]=l1*l1; ptab[pi*6+1]=l2*l2; ptab[pi*6+2]=l3*l3;
        ptab[pi*6+3]=(l1+l2+l3)&1; ptab[pi*6+4]=sbase; ptab[pi*6+5]=2*l3+1;
        sbase+=2*l3+1; pi++;
      }
    }
  }
  if(t>=15625) return;
  int i=t/625, j=(t/25)%25, k=t%25;
  double fact[14]; fact[0]=1.0;
  for(int m=1;m<14;m++) fact[m]=fact[m-1]*(double)m;
  int li=l_of_idx(i), lj=l_of_idx(j), lk=l_of_idx(k);
  int ca[2],cb[2],cc[2]; double ra[2],ia_[2],rb[2],ib_[2],rc[2],ic_[2];
  int na=urow_dev(i,li,ca,ra,ia_);
  int nb=urow_dev(j,lj,cb,rb,ib_);
  int nc=urow_dev(k,lk,cc,rc,ic_);
  double Tre=0.0,Tim=0.0;
  for(int a=0;a<na;a++)for(int b=0;b<nb;b++)for(int c=0;c<nc;c++){
    int ma=ca[a]-li*li-li, mb=cb[b]-lj*lj-lj, mc=cc[c]-lk*lk-lk;
    double cg=cg_complex_dev(li,ma,lj,mb,lk,mc,fact);
    if(cg==0.0) continue;
    double xre = ra[a]*rb[b]-ia_[a]*ib_[b];
    double xim = ra[a]*ib_[b]+ia_[a]*rb[b];
    double wre = xre*rc[c]+xim*ic_[c];
    double wim = xim*rc[c]-xre*ic_[c];
    Tre += wre*cg; Tim += wim*cg;
  }
  double C = Tre+Tim;
  if(fabs(C)<1e-12) C=0.0;
  CGd[t]=(float)C;
}

__global__ __launch_bounds__(16) void k_entries(const float* __restrict__ CGd, const int* __restrict__ ptab,
                                                int* eidx, float* eval_, int* ecnt){
  int pi=blockIdx.x, c=threadIdx.x;
  int l1sq=ptab[pi*6], l2sq=ptab[pi*6+1], l3sq=ptab[pi*6+2];
  int sbase=ptab[pi*6+4], n3=ptab[pi*6+5];
  if(c>=n3) return;
  int l1=l_of_idx(l1sq), l2=l_of_idx(l2sq);
  int slot=sbase+c, cntv=0;
  for(int ia=0; ia<2*l1+1; ia++)
    for(int ib=0; ib<2*l2+1; ib++){
      float v = CGd[(l1sq+ia)*625 + (l2sq+ib)*25 + (l3sq+c)];
      if(v!=0.0f){ eidx[slot*MAXE+cntv]=ia|(ib<<8); eval_[slot*MAXE+cntv]=v; cntv++; }
    }
  ecnt[slot]=cntv;
}

// ======================= edge stage =======================

__global__ __launch_bounds__(256) void k_edge(const int* __restrict__ Z, const int* __restrict__ nbr,
    const float* __restrict__ disp, const float* __restrict__ Wsp,
    float* __restrict__ g, float* __restrict__ Ye, int* cnt, int E){
  int e=blockIdx.x*256+threadIdx.x; if(e>=E) return;
  int i0=nbr[2*e], j0=nbr[2*e+1];
  atomicAdd(&cnt[i0],1);
  int z=Z[j0];
  float dx=disp[3*e], dy=disp[3*e+1], dz=disp[3*e+2];
  float r=sqrtf(dx*dx+dy*dy+dz*dz+1e-12f);
  float inv=1.0f/r;
  float x=dx*inv, y=dy*inv, zz=dz*inv;
  float rc=fminf(r*0.2f,1.0f);
  float fc=0.5f*(cosf(3.14159265358979323846f*rc)+1.0f);
  float rbf[16];
  #pragma unroll
  for(int k=0;k<16;k++){
    float d=r-(float)k*(5.0f/15.0f);
    rbf[k]=expf(-10.24f*d*d)*fc;
  }
  const float* Wz=Wsp + z*256;
  #pragma unroll
  for(int rr=0;rr<16;rr++){
    float s=0.f;
    #pragma unroll
    for(int k=0;k<16;k++) s += rbf[k]*Wz[k*16+rr];
    g[e*16+rr]=s;
  }
  float x2=x*x,y2=y*y,z2=zz*zz;
  float* Y=Ye+(size_t)e*25;
  Y[0]=0.28209479177387814f;
  Y[1]=0.4886025119029199f*y;
  Y[2]=0.4886025119029199f*zz;
  Y[3]=0.4886025119029199f*x;
  Y[4]=1.0925484305920792f*x*y;
  Y[5]=1.0925484305920792f*y*zz;
  Y[6]=0.31539156525252005f*(3.f*z2-1.f);
  Y[7]=1.0925484305920792f*x*zz;
  Y[8]=0.5462742152960396f*(x2-y2);
  Y[9]=0.5900435899266435f*y*(3.f*x2-y2);
  Y[10]=2.890611442640554f*x*y*zz;
  Y[11]=0.4570457994644658f*y*(5.f*z2-1.f);
  Y[12]=0.3731763325901154f*zz*(5.f*z2-3.f);
  Y[13]=0.4570457994644658f*x*(5.f*z2-1.f);
  Y[14]=1.445305721320277f*zz*(x2-y2);
  Y[15]=0.5900435899266435f*x*(x2-3.f*y2);
  Y[16]=2.5033429417967046f*x*y*(x2-y2);
  Y[17]=1.7701307697799304f*y*zz*(3.f*x2-y2);
  Y[18]=0.9461746957575601f*x*y*(7.f*z2-1.f);
  Y[19]=0.6690465435572892f*y*zz*(7.f*z2-3.f);
  Y[20]=0.10578554691520431f*(35.f*z2*z2-30.f*z2+3.f);
  Y[21]=0.6690465435572892f*x*zz*(7.f*z2-3.f);
  Y[22]=0.47308734787878004f*(x2-y2)*(7.f*z2-1.f);
  Y[23]=1.7701307697799304f*x*zz*(x2-3.f*y2);
  Y[24]=0.6258357354491761f*(x2*x2-6.f*x2*y2+y2*y2);
}

// ======================= CSR build =======================

__global__ __launch_bounds__(1024) void k_scan(const int* __restrict__ cnt, int* offs, int* cursor, int N){
  __shared__ int part[1024];
  int t=threadIdx.x;
  int per=(N+1023)>>10;
  int start=t*per;
  int s=0;
  for(int i2=0;i2<per;i2++){int idx=start+i2; if(idx<N) s+=cnt[idx];}
  part[t]=s; __syncthreads();
  for(int off=1;off<1024;off<<=1){
    int v=(t>=off)?part[t-off]:0;
    __syncthreads();
    part[t]+=v;
    __syncthreads();
  }
  int run=(t>0)?part[t-1]:0;
  for(int i2=0;i2<per;i2++){int idx=start+i2; if(idx<N){offs[idx]=run; cursor[idx]=run; run+=cnt[idx];}}
  if(t==1023) offs[N]=part[1023];
}

__global__ __launch_bounds__(256) void k_fill(const int* __restrict__ nbr, int* cursor, int* elist, int E){
  int e=blockIdx.x*256+threadIdx.x; if(e>=E)return;
  int pos=atomicAdd(&cursor[nbr[2*e]],1);
  elist[pos]=e;
}

// ======================= aggregation: y0 -> d_out ch 0..15 =======================

__global__ __launch_bounds__(64) void k_agg(const float* __restrict__ g, const float* __restrict__ Ye,
    const int* __restrict__ offs, const int* __restrict__ elist, const float* __restrict__ norm,
    float* __restrict__ y){
  int n=blockIdx.x, t=threadIdx.x;
  __shared__ float gs[16];
  __shared__ float ys[25];
  float acc[7];
  #pragma unroll
  for(int i2=0;i2<7;i2++) acc[i2]=0.f;
  int e0=offs[n], e1=offs[n+1];
  for(int ei=e0; ei<e1; ei++){
    int e=elist[ei];
    if(t<16) gs[t]=g[(size_t)e*16+t];
    else if(t<41) ys[t-16]=Ye[(size_t)e*25+t-16];
    __syncthreads();
    #pragma unroll
    for(int i2=0;i2<7;i2++){
      int o=t+64*i2;
      if(o<400) acc[i2] += ys[o>>4]*gs[o&15];
    }
    __syncthreads();
  }
  float nv=1.0f/norm[0];
  float* yo=y+(size_t)n*7200;
  #pragma unroll
  for(int i2=0;i2<7;i2++){
    int o=t+64*i2;
    if(o<400){ int lm=o>>4,k=o&15; yo[lm*144+k]=acc[i2]*nv; yo[3600+lm*144+k]=0.f; }
  }
}

// ======================= TP layer 0 — 4 waves/atom =======================
// wave split: degree-dense by l-group, CG paths by pi%4, outS via LDS atomicAdd.

__global__ __launch_bounds__(256,3) void k_tp0(float* __restrict__ y, const float* __restrict__ W1,
    const float* __restrict__ W2, const float* __restrict__ wp, const int* __restrict__ ptab,
    const int* __restrict__ eidx, const float* __restrict__ eval_, const int* __restrict__ ecnt){
  int n=blockIdx.x, tid=threadIdx.x, f=tid&63, wv=tid>>6;
  __shared__ float y0s[400];
  __shared__ float aS[1600];
  __shared__ float bS[1600];
  __shared__ float outS[3200];
  const float* yin = y + (size_t)n*7200;
  for(int t=tid;t<400;t+=256) y0s[t] = yin[(t>>4)*144 + (t&15)];
  for(int t=tid;t<3200;t+=256) outS[t]=0.f;
  __syncthreads();
  // degree-dense, parity 0 only; l-group -> wave: {l0:w3, l1:w3, l2:w2, l3:w1, l4:w0}
  const int asg0[5]={3,3,2,1,0};
  #pragma unroll
  for(int l=0;l<5;l++){
    if(asg0[l]!=wv) continue;
    const int n1=2*l+1, base=l*l;
    float accA[9],accB[9];
    #pragma unroll
    for(int j2=0;j2<9;j2++){accA[j2]=0.f;accB[j2]=0.f;}
    const float* w1=W1+l*1024+f;
    const float* w2=W2+l*1024+f;
    for(int k=0;k<16;k++){
      float u1=w1[k*64], u2=w2[k*64];
      #pragma unroll
      for(int j2=0;j2<n1;j2++){
        float yv=y0s[(base+j2)*16+k];
        accA[j2]+=yv*u1; accB[j2]+=yv*u2;
      }
    }
    #pragma unroll
    for(int j2=0;j2<n1;j2++){ aS[(base+j2)*64+f]=accA[j2]; bS[(base+j2)*64+f]=accB[j2]; }
  }
  __syncthreads();
  for(int pi=0;pi<NPATH;pi++){
    if((pi&3)!=wv) continue;
    int l1sq=ptab[pi*6], l2sq=ptab[pi*6+1], l3sq=ptab[pi*6+2];
    int s=ptab[pi*6+3], sbase=ptab[pi*6+4], n3=ptab[pi*6+5];
    float w00=wp[pi*256+f];
    for(int c=0;c<n3;c++){
      int slot=sbase+c;
      int cntv=ecnt[slot];
      const int* ei=eidx+slot*MAXE;
      const float* ev=eval_+slot*MAXE;
      float r=0.f;
      for(int j2=0;j2<cntv;j2++){
        int e=ei[j2]; float v=ev[j2];
        r += v*aS[(l1sq+(e&255))*64+f]*bS[(l2sq+(e>>8))*64+f];
      }
      atomicAdd(&outS[(s*25+l3sq+c)*64+f], w00*r);
    }
  }
  __syncthreads();
  float* yo = y + (size_t)n*7200 + 16;
  for(int t2=wv;t2<50;t2+=4) yo[t2*144+f]=outS[t2*64+f];
}

// ======================= TP layer 1 — 4 waves/atom =======================
// bufA unioned: input staging first, then zeroed and reused as outS.

__global__ __launch_bounds__(256,3) void k_tp1(float* __restrict__ y, const float* __restrict__ W1,
    const float* __restrict__ W2, const float* __restrict__ wp, const int* __restrict__ ptab,
    const int* __restrict__ eidx, const float* __restrict__ eval_, const int* __restrict__ ecnt){
  int n=blockIdx.x, tid=threadIdx.x, f=tid&63, wv=tid>>6;
  __shared__ float bufA[3200];          // y1s, then outS
  __shared__ float2 aS[1600];           // [lm*64+f] = (parity0, parity1)
  __shared__ float2 bS[1600];
  const float* yin = y + (size_t)n*7200 + 16;
  for(int t=tid;t<3200;t+=256) bufA[t]=yin[(t>>6)*144+(t&63)];
  __syncthreads();
  // group g=p*5+l -> wave: balanced {g0:2,g1:0,g2:2,g3:2,g4:0,g5:3,g6:1,g7:3,g8:3,g9:1}
  const int asg[10]={2,0,2,2,0,3,1,3,3,1};
  #pragma unroll
  for(int p=0;p<2;p++){
    #pragma unroll
    for(int l=0;l<5;l++){
      if(asg[p*5+l]!=wv) continue;
      const int n1=2*l+1, base=l*l;
      float accA[9],accB[9];
      #pragma unroll
      for(int j2=0;j2<9;j2++){accA[j2]=0.f;accB[j2]=0.f;}
      const float* w1=W1+(p*5+l)*4096+f;
      const float* w2=W2+(p*5+l)*4096+f;
      for(int k=0;k<64;k++){
        float u1=w1[k*64], u2=w2[k*64];
        #pragma unroll
        for(int j2=0;j2<n1;j2++){
          float yv=bufA[(p*25+base+j2)*64+k];
          accA[j2]+=yv*u1; accB[j2]+=yv*u2;
        }
      }
      #pragma unroll
      for(int j2=0;j2<n1;j2++){
        if(p==0){ aS[(base+j2)*64+f].x=accA[j2]; bS[(base+j2)*64+f].x=accB[j2]; }
        else    { aS[(base+j2)*64+f].y=accA[j2]; bS[(base+j2)*64+f].y=accB[j2]; }
      }
    }
  }
  __syncthreads();
  for(int t=tid;t<3200;t+=256) bufA[t]=0.f;   // bufA becomes outS
  __syncthreads();
  for(int pi=0;pi<NPATH;pi++){
    if((pi&3)!=wv) continue;
    int l1sq=ptab[pi*6], l2sq=ptab[pi*6+1], l3sq=ptab[pi*6+2];
    int s=ptab[pi*6+3], sbase=ptab[pi*6+4], n3=ptab[pi*6+5];
    float w00=wp[pi*256+f], w01=wp[pi*256+64+f], w10=wp[pi*256+128+f], w11=wp[pi*256+192+f];
    for(int c=0;c<n3;c++){
      int slot=sbase+c;
      int cntv=ecnt[slot];
      const int* ei=eidx+slot*MAXE;
      const float* ev=eval_+slot*MAXE;
      float r00=0.f,r01=0.f,r10=0.f,r11=0.f;
      for(int j2=0;j2<cntv;j2++){
        int e=ei[j2]; float v=ev[j2];
        float2 av=aS[(l1sq+(e&255))*64+f];
        float2 bv=bS[(l2sq+(e>>8))*64+f];
        r00+=v*av.x*bv.x; r01+=v*av.x*bv.y; r10+=v*av.y*bv.x; r11+=v*av.y*bv.y;
      }
      atomicAdd(&bufA[(s*25+l3sq+c)*64+f],     w00*r00+w11*r11);   // even
      atomicAdd(&bufA[((1-s)*25+l3sq+c)*64+f], w01*r01+w10*r10);   // odd
    }
  }
  __syncthreads();
  float* yo=y+(size_t)n*7200+80;
  for(int t2=wv;t2<50;t2+=4) yo[t2*144+f]=bufA[t2*64+f];
}

// ======================= final =======================

__device__ const int DEGLM[25]={0,1,1,1,2,2,2,2,2,3,3,3,3,3,3,3,4,4,4,4,4,4,4,4,4};

__global__ __launch_bounds__(128) void k_final(float* __restrict__ y, const int* __restrict__ Z,
    const float* __restrict__ emb, const float* __restrict__ Wet, const float* __restrict__ bet,
    const float* __restrict__ wf){
  int n=blockIdx.x, t=threadIdx.x;
  __shared__ float embs[64];
  __shared__ float teS[144];
  int z=Z[n];
  if(t<64) embs[t]=emb[z*64+t];
  __syncthreads();
  for(int c=t;c<144;c+=128){
    float s=bet[c];
    for(int d=0;d<64;d++) s+=embs[d]*Wet[d*144+c];
    teS[c]=s;
  }
  __syncthreads();
  float* yo=y+(size_t)n*7200;
  for(int row=0;row<50;row++){
    int p=row/25, lm=row-25*p;
    const float* wrow=wf+(p*5+DEGLM[lm])*144;
    for(int c=t;c<144;c+=128){
      float v=yo[row*144+c];
      float te=teS[c];
      v=te*v*wrow[c];
      if(row==0) v+=te;
      float sp=log1pf(expf(v));
      v=v+v*tanhf(sp);
      yo[row*144+c]=v;
    }
  }
}

// ======================= launch =======================

extern "C" void kernel_launch(void* const* d_in, const int* in_sizes, int n_in,
                              void* d_out, int out_size, void* d_ws, size_t ws_size,
                              hipStream_t stream) {
  const int*   Z    =(const int*)  d_in[0];
  const int*   nbr  =(const int*)  d_in[1];
  const float* disp =(const float*)d_in[2];
  const float* Wsp  =(const float*)d_in[3];
  const float* emb  =(const float*)d_in[4];
  const float* Wet  =(const float*)d_in[5];
  const float* bet  =(const float*)d_in[6];
  const float* norm =(const float*)d_in[7];
  const float* t0W1 =(const float*)d_in[8];
  const float* t0W2 =(const float*)d_in[9];
  const float* t0wp =(const float*)d_in[10];
  const float* t1W1 =(const float*)d_in[11];
  const float* t1W2 =(const float*)d_in[12];
  const float* t1wp =(const float*)d_in[13];
  const float* wf   =(const float*)d_in[14];
  int N=in_sizes[0];
  int E=in_sizes[1]/2;
  float* y=(float*)d_out;

  char* w=(char*)d_ws;
  size_t off=0;
  auto take=[&](size_t bytes)->void*{ size_t cur=(off+255)&~(size_t)255; off=cur+bytes; return (void*)(w+cur); };
  float* CGd   =(float*)take(15625*4);
  int*   ptab  =(int*)  take(NPATH*6*4);
  int*   eidx  =(int*)  take((size_t)NSLOT*MAXE*4);
  float* eval_ =(float*)take((size_t)NSLOT*MAXE*4);
  int*   ecnt  =(int*)  take(NSLOT*4);
  int*   cnt   =(int*)  take((size_t)N*4);
  int*   offs  =(int*)  take((size_t)(N+1)*4);
  int*   cursor=(int*)  take((size_t)N*4);
  int*   elist =(int*)  take((size_t)E*4);
  float* g     =(float*)take((size_t)E*16*4);
  float* Ye    =(float*)take((size_t)E*25*4);
  (void)ws_size; (void)out_size; (void)n_in;

  k_cg     <<<dim3((15625+63)/64), dim3(64),  0, stream>>>(CGd, ptab, cnt, N);
  k_entries<<<dim3(NPATH),         dim3(16),  0, stream>>>(CGd, ptab, eidx, eval_, ecnt);
  k_edge   <<<dim3((E+255)/256),   dim3(256), 0, stream>>>(Z, nbr, disp, Wsp, g, Ye, cnt, E);
  k_scan   <<<dim3(1),             dim3(1024),0, stream>>>(cnt, offs, cursor, N);
  k_fill   <<<dim3((E+255)/256),   dim3(256), 0, stream>>>(nbr, cursor, elist, E);
  k_agg    <<<dim3(N),             dim3(64),  0, stream>>>(g, Ye, offs, elist, norm, y);
  k_tp0    <<<dim3(N),             dim3(256), 0, stream>>>(y, t0W1, t0W2, t0wp, ptab, eidx, eval_, ecnt);
  k_tp1    <<<dim3(N),             dim3(256), 0, stream>>>(y, t1W1, t1W2, t1wp, ptab, eidx, eval_, ecnt);
  k_final  <<<dim3(N),             dim3(128), 0, stream>>>(y, Z, emb, Wet, bet, wf);
}